// Round 6
// baseline (191.567 us; speedup 1.0000x reference)
//
#include <hip/hip_runtime.h>
#include <hip/hip_bf16.h>

typedef __attribute__((ext_vector_type(8))) short short8;
typedef __attribute__((ext_vector_type(4))) float floatx4;
typedef __attribute__((ext_vector_type(16))) float floatx16;

#define LOG2E_OVER_8 0.18033688011112042f
#define NKT 8   // 32-key steps per wave (256 keys/wave, 1024/block, out-split 4)

__device__ __forceinline__ unsigned short f2bf(float f) {  // RNE
    union { float f; unsigned u; } v; v.f = f;
    unsigned r = v.u + 0x7fffu + ((v.u >> 16) & 1u);
    return (unsigned short)(r >> 16);
}
__device__ __forceinline__ unsigned pack_rne(float a, float b) {
    union { float f; unsigned u; } ua, ub; ua.f = a; ub.f = b;
    unsigned ta = ua.u + 0x7fffu + ((ua.u >> 16) & 1u);
    unsigned tb = ub.u + 0x7fffu + ((ub.u >> 16) & 1u);
    return __builtin_amdgcn_perm(tb, ta, 0x07060302u);
}
__device__ __forceinline__ unsigned pack_hu(float a, float b) {  // round-half-up
    union { float f; unsigned u; } ua, ub; ua.f = a; ub.f = b;
    return __builtin_amdgcn_perm(ub.u + 0x8000u, ua.u + 0x8000u, 0x07060302u);
}

// ---------------- Kernel 0: W -> Wt bf16 [3][64][512], coalesced reads ------
__global__ __launch_bounds__(256) void wtrans_k(const float* __restrict__ Wq,
                                                const float* __restrict__ Wk,
                                                const float* __restrict__ Wv,
                                                unsigned short* __restrict__ Wt) {
    int idx = blockIdx.x * 256 + threadIdx.x;   // 98304
    int p = idx >> 15, rem = idx & 32767;
    int k = rem >> 6;      // 0..511
    int n = rem & 63;      // lane-fast -> coalesced read of W
    const float* W = (p == 0) ? Wq : ((p == 1) ? Wk : Wv);
    Wt[p * 32768 + n * 512 + k] = f2bf(W[k * 64 + n]);
}

// ---------------- Kernel 1: QKV projection, N-split for occupancy -----------
// grid 2048 x 128 thr (2 waves). Block = 16 rows x half the N-tiles.
// Wave = 16 rows x 3 N-tiles; depth-4 rotating x prefetch. Q pre-scaled.
__global__ __launch_bounds__(128) void proj_k(const float* __restrict__ x,
                                              const unsigned short* __restrict__ Wt,
                                              const float* __restrict__ bq,
                                              const float* __restrict__ bk,
                                              const float* __restrict__ bv,
                                              unsigned short* __restrict__ Qb,
                                              unsigned short* __restrict__ Kb,
                                              unsigned short* __restrict__ Vt) {
    int tid = threadIdx.x, l = tid & 63, wv = tid >> 6;   // wv 0/1
    int m = l & 15, quad = l >> 4;
    int strip = blockIdx.x >> 1, hb = blockIdx.x & 1;
    int row0 = strip * 16;
    int wt4 = hb * 2 + wv;          // which quarter of the 12 N-tiles

    const float* xrow = x + (row0 + m) * 512 + quad * 8;
    const unsigned short* wbase = Wt + (wt4 * 48 + m) * 512 + quad * 8;

    floatx4 acc[3];
#pragma unroll
    for (int i = 0; i < 3; i++) acc[i] = (floatx4)(0.f);

    float4 xp0[4], xp1[4];
#pragma unroll
    for (int i = 0; i < 4; i++) {
        xp0[i] = *(const float4*)(xrow + i * 32);
        xp1[i] = *(const float4*)(xrow + i * 32 + 4);
    }

#pragma unroll
    for (int kc = 0; kc < 16; kc++) {
        int slot = kc & 3;
        union { unsigned u[4]; short8 s; } av;
        av.u[0] = pack_rne(xp0[slot].x, xp0[slot].y);
        av.u[1] = pack_rne(xp0[slot].z, xp0[slot].w);
        av.u[2] = pack_rne(xp1[slot].x, xp1[slot].y);
        av.u[3] = pack_rne(xp1[slot].z, xp1[slot].w);
        if (kc + 4 < 16) {
            xp0[slot] = *(const float4*)(xrow + (kc + 4) * 32);
            xp1[slot] = *(const float4*)(xrow + (kc + 4) * 32 + 4);
        }
#pragma unroll
        for (int ct = 0; ct < 3; ct++) {
            short8 b = *(const short8*)(wbase + ct * 8192 + kc * 32);
            acc[ct] = __builtin_amdgcn_mfma_f32_16x16x32_bf16(av.s, b, acc[ct], 0, 0, 0);
        }
    }

#pragma unroll
    for (int ct = 0; ct < 3; ct++) {
        int ctg = wt4 * 3 + ct;
        int col = ctg * 16 + m;
        float bias = (ctg < 4) ? bq[col] : ((ctg < 8) ? bk[col - 64] : bv[col - 128]);
        if (ctg < 8) {
            unsigned short* dst = (ctg < 4) ? Qb : Kb;
            float scl = (ctg < 4) ? LOG2E_OVER_8 : 1.0f;
            int d = (ctg & 3) * 16 + m;
#pragma unroll
            for (int r = 0; r < 4; r++) {
                int row = row0 + quad * 4 + r;
                dst[row * 64 + d] = f2bf((acc[ct][r] + bias) * scl);
            }
        } else {
            int d = (ctg - 8) * 16 + m;
            int row = row0 + quad * 4;
            int bb = row >> 12, sq = row & 4095;
            unsigned long long pk = 0;
#pragma unroll
            for (int r = 0; r < 4; r++)
                pk |= ((unsigned long long)f2bf(acc[ct][r] + bias)) << (16 * r);
            *(unsigned long long*)(Vt + ((bb * 64 + d) * 4096 + sq)) = pk;
        }
    }
}

// ---------------- Kernel 2: attention, XCD-aligned K/V slices ---------------
// grid 2048, 256 thr. Block = (os, b, 32-q tile); 4 waves = 4x 256-key slices.
// Index swizzle: blocks sharing a (os,b) K/V-slice have equal bid mod 16 ->
// same XCD -> slice stays in that XCD's L2 (512 KB per XCD total).
__global__ __launch_bounds__(256) void attn_k(const unsigned short* __restrict__ Qb,
                                              const unsigned short* __restrict__ Kb,
                                              const unsigned short* __restrict__ Vt,
                                              const int* __restrict__ mask,
                                              float* __restrict__ Np,
                                              float* __restrict__ Dp) {
    __shared__ __align__(16) float obuf[3][64][32];   // 24 KB partial O's
    __shared__ float dsh[4][32];

    int tid = threadIdx.x, l = tid & 63, wv = tid >> 6;
    int n = l & 31, h = l >> 5;
    int bid = blockIdx.x;
    int qt = bid >> 4, grp = bid & 15;     // XCD-aligned group decode
    int os = grp >> 2, b = grp & 3;
    int q0 = qt * 32;
    int kbase = os * 1024 + wv * 256;

    const int* maskb = mask + b * 4096 + kbase;
    int az = 0;
#pragma unroll
    for (int i = 0; i < 4; i++) az |= (maskb[l + i * 64] == 0);
    const bool hasz = __any(az);

    const unsigned short* Qg = Qb + (b * 4096 + q0 + n) * 64 + h * 8;
    short8 qf[4];
#pragma unroll
    for (int c = 0; c < 4; c++) qf[c] = *(const short8*)(Qg + c * 16);

    const unsigned short* Kg = Kb + (b * 4096 + kbase + n) * 64 + h * 8;
    const unsigned short* Vg = Vt + b * 262144 + n * 4096 + kbase + h * 8;

    floatx16 o0 = (floatx16)(0.f), o1 = (floatx16)(0.f);
    floatx4 dacc = (floatx4)(0.f);

    short8 kf[4], kfn[4];
#pragma unroll
    for (int c = 0; c < 4; c++) kf[c] = *(const short8*)(Kg + c * 16);

#pragma unroll 2
    for (int kt = 0; kt < NKT; kt++) {
        short8 vf[4];
        vf[0] = *(const short8*)(Vg + kt * 32);
        vf[1] = *(const short8*)(Vg + kt * 32 + 16);
        vf[2] = *(const short8*)(Vg + 131072 + kt * 32);
        vf[3] = *(const short8*)(Vg + 131072 + kt * 32 + 16);

        floatx16 sf = (floatx16)(0.f);
#pragma unroll
        for (int c = 0; c < 4; c++)
            sf = __builtin_amdgcn_mfma_f32_32x32x16_bf16(kf[c], qf[c], sf, 0, 0, 0);

        if (kt + 1 < NKT) {
#pragma unroll
            for (int c = 0; c < 4; c++)
                kfn[c] = *(const short8*)(Kg + (kt + 1) * 2048 + c * 16);
        }

        unsigned pr[8];
#pragma unroll
        for (int j = 0; j < 8; j++) {
            float p0 = exp2f(sf[2 * j]);       // Q pre-scaled by log2(e)/8
            float p1 = exp2f(sf[2 * j + 1]);
            dacc[j & 3] += p0 + p1;
            if (hasz) {   // post-softmax -inf fill (rare path)
                int r0 = (2 * j & 3) + 8 * (j >> 1) + 4 * h;
                if (maskb[kt * 32 + r0] == 0)     p0 = -__builtin_inff();
                if (maskb[kt * 32 + r0 + 1] == 0) p1 = -__builtin_inff();
            }
            pr[j] = pack_hu(p0, p1);
        }
        unsigned xr[8];
#pragma unroll
        for (int j = 0; j < 8; j++) xr[j] = __shfl_xor((int)pr[j], 32, 64);

        union { unsigned u[4]; short8 s; } pb0, pb1;
        pb0.u[0] = h ? xr[2] : pr[0];  pb0.u[1] = h ? xr[3] : pr[1];
        pb0.u[2] = h ? pr[2] : xr[0];  pb0.u[3] = h ? pr[3] : xr[1];
        pb1.u[0] = h ? xr[6] : pr[4];  pb1.u[1] = h ? xr[7] : pr[5];
        pb1.u[2] = h ? pr[6] : xr[4];  pb1.u[3] = h ? pr[7] : xr[5];

        o0 = __builtin_amdgcn_mfma_f32_32x32x16_bf16(vf[0], pb0.s, o0, 0, 0, 0);
        o0 = __builtin_amdgcn_mfma_f32_32x32x16_bf16(vf[1], pb1.s, o0, 0, 0, 0);
        o1 = __builtin_amdgcn_mfma_f32_32x32x16_bf16(vf[2], pb0.s, o1, 0, 0, 0);
        o1 = __builtin_amdgcn_mfma_f32_32x32x16_bf16(vf[3], pb1.s, o1, 0, 0, 0);

#pragma unroll
        for (int c = 0; c < 4; c++) kf[c] = kfn[c];
    }

    // per-wave denominator (keys of this wave), cross-half reduce
    float dl = (dacc[0] + dacc[1]) + (dacc[2] + dacc[3]);
    dl += __shfl_xor(dl, 32, 64);
    if (h == 0) dsh[wv][n] = dl;

    // in-block reduction of the 4 key-slices
    if (wv > 0) {
#pragma unroll
        for (int i = 0; i < 16; i++) {
            int d = (i & 3) + 8 * (i >> 2) + 4 * h;
            obuf[wv - 1][d][n]      = o0[i];
            obuf[wv - 1][d + 32][n] = o1[i];
        }
    }
    __syncthreads();
    if (wv == 0) {
#pragma unroll
        for (int i = 0; i < 16; i++) {
            int d = (i & 3) + 8 * (i >> 2) + 4 * h;
            o0[i] += (obuf[0][d][n] + obuf[1][d][n]) + obuf[2][d][n];
            o1[i] += (obuf[0][d + 32][n] + obuf[1][d + 32][n]) + obuf[2][d + 32][n];
        }
        float dtot = (dsh[0][n] + dsh[1][n]) + (dsh[2][n] + dsh[3][n]);
        int rowbase = os * 16384 + b * 4096 + q0;
        if (h == 0) Dp[rowbase + n] = dtot;

        __builtin_amdgcn_s_waitcnt(0);       // all LDS reads returned
        float* T = &obuf[0][0][0];           // reuse as 32 x 68 transpose buf
#pragma unroll
        for (int i = 0; i < 16; i++) {
            int d = (i & 3) + 8 * (i >> 2) + 4 * h;
            T[n * 68 + d]      = o0[i];
            T[n * 68 + 32 + d] = o1[i];
        }
        __builtin_amdgcn_s_waitcnt(0);       // wave-private: no barrier needed
#pragma unroll
        for (int g = 0; g < 8; g++) {
            int idx = g * 64 + l;
            int row = idx >> 4, c4 = (idx & 15) * 4;
            float4 v = *(const float4*)(T + row * 68 + c4);
            *(float4*)(Np + (rowbase + row) * 64 + c4) = v;
        }
    }
}

// ---------------- Kernel 3: combine 4 key-split partials --------------------
__global__ __launch_bounds__(256) void combine_k(const float* __restrict__ Np,
                                                 const float* __restrict__ Dp,
                                                 float* __restrict__ out) {
    int g = blockIdx.x * 256 + threadIdx.x;   // 1,048,576
    int row = g >> 6;
    float nu = 0.f, d = 0.f;
#pragma unroll
    for (int sp = 0; sp < 4; sp++) {
        nu += Np[sp * 1048576 + g];
        d  += Dp[sp * 16384 + row];
    }
    out[g] = nu / d;
}

extern "C" void kernel_launch(void* const* d_in, const int* in_sizes, int n_in,
                              void* d_out, int out_size, void* d_ws, size_t ws_size,
                              hipStream_t stream) {
    const float* x  = (const float*)d_in[0];
    const int* mask = (const int*)d_in[1];
    const float* Wq = (const float*)d_in[2];
    const float* bq = (const float*)d_in[3];
    const float* Wk = (const float*)d_in[4];
    const float* bk = (const float*)d_in[5];
    const float* Wv = (const float*)d_in[6];
    const float* bv = (const float*)d_in[7];
    float* out = (float*)d_out;

    char* ws = (char*)d_ws;
    unsigned short* Wt = (unsigned short*)(ws);              // 192 KB
    unsigned short* Qb = (unsigned short*)(ws + 0x40000);    // 2 MB
    unsigned short* Kb = (unsigned short*)(ws + 0x240000);   // 2 MB
    unsigned short* Vt = (unsigned short*)(ws + 0x440000);   // 2 MB
    float*          Dp = (float*)(ws + 0x640000);            // 256 KB [4][16384]
    float*          Np = (float*)(ws + 0x6C0000);            // 16.78 MB [4][16384][64]

    wtrans_k<<<384, 256, 0, stream>>>(Wq, Wk, Wv, Wt);
    proj_k<<<2048, 128, 0, stream>>>(x, Wt, bq, bk, bv, Qb, Kb, Vt);
    attn_k<<<2048, 256, 0, stream>>>(Qb, Kb, Vt, mask, Np, Dp);
    combine_k<<<4096, 256, 0, stream>>>(Np, Dp, out);
}